// Round 6
// baseline (493.098 us; speedup 1.0000x reference)
//
#include <hip/hip_runtime.h>
#include <cstdint>

#define WID   160
#define HEI   160
#define HWPIX (WID * HEI)   // 25600
#define CIN_  64
#define COUT_ 64
#define BATCH 32
#define PW    162           // padded width/height (zero border layout; border
                            // cells are NEVER value-read -> may hold poison)
#define PPIX  (PW * PW)     // 26244
#define NINT   6004         // interior 4-px groups per image (158 rows x 38)
#define BSTART 6016         // border tids start (wave-aligned gap after NINT)
#define NBORD  396          // border 4-px groups per image (80 + 316)

// ---------------------------------------------------------------------------
// Kernel 1 (FUSED wprep + binpack).
//  blockIdx.x < 25 : binpack. Thread = 4 consecutive pixels x 64 channels,
//                    float4 loads, one u64 store per pixel into padded layout.
//  blockIdx.x == 25: weight prep, blockIdx.y<16, wave w handles
//                    co = blockIdx.y*4 + w (lane = ci, 64-lane ballot).
// Disjoint outputs; conv dispatch serializes after on the same stream.
// ---------------------------------------------------------------------------
__global__ __launch_bounds__(256) void prep_kernel(const float* __restrict__ x,
                                                   const float* __restrict__ w,
                                                   uint64_t* __restrict__ packed,
                                                   uint64_t* __restrict__ wpack,
                                                   float* __restrict__ alpha) {
    if (blockIdx.x == 25) {
        if (blockIdx.y >= 16) return;
        const int wv = threadIdx.x >> 6;          // wave 0..3
        const int ci = threadIdx.x & 63;          // lane = input channel
        const int co = blockIdx.y * 4 + wv;       // 0..63
        const float* wp = w + ((size_t)co * CIN_ + ci) * 9;
        float vals[9];
        float s = 0.0f;
#pragma unroll
        for (int t = 0; t < 9; ++t) {
            float v = wp[t];
            vals[t] = v;
            s += fminf(fabsf(v), 1.0f);
        }
#pragma unroll
        for (int t = 0; t < 9; ++t) {
            unsigned long long m = __ballot(vals[t] > 0.0f);
            if (ci == 0) wpack[co * 9 + t] = m;
        }
#pragma unroll
        for (int off = 32; off > 0; off >>= 1) s += __shfl_down(s, off);
        if (ci == 0) alpha[co] = s * (1.0f / 576.0f);
        return;
    }

    const int t  = blockIdx.x * 256 + threadIdx.x;   // 0..6399
    const int b  = blockIdx.y;
    const int p4 = t * 4;
    const int y  = p4 / WID;
    const int x0 = p4 - y * WID;
    const float4* xp = (const float4*)(x + (size_t)b * CIN_ * HWPIX + p4);

    uint32_t lo[4] = {0, 0, 0, 0}, hi[4] = {0, 0, 0, 0};
#pragma unroll
    for (int ci = 0; ci < 32; ++ci) {
        float4 v = xp[(size_t)ci * (HWPIX / 4)];
        lo[0] |= (uint32_t)(v.x > 0.0f) << ci;
        lo[1] |= (uint32_t)(v.y > 0.0f) << ci;
        lo[2] |= (uint32_t)(v.z > 0.0f) << ci;
        lo[3] |= (uint32_t)(v.w > 0.0f) << ci;
    }
#pragma unroll
    for (int ci = 0; ci < 32; ++ci) {
        float4 v = xp[(size_t)(ci + 32) * (HWPIX / 4)];
        hi[0] |= (uint32_t)(v.x > 0.0f) << ci;
        hi[1] |= (uint32_t)(v.y > 0.0f) << ci;
        hi[2] |= (uint32_t)(v.z > 0.0f) << ci;
        hi[3] |= (uint32_t)(v.w > 0.0f) << ci;
    }
    uint64_t* dst = packed + (size_t)b * PPIX + (size_t)(y + 1) * PW + (x0 + 1);
#pragma unroll
    for (int i = 0; i < 4; ++i)
        dst[i] = ((uint64_t)hi[i] << 32) | lo[i];
}

// ---------------------------------------------------------------------------
// Kernel 2: conv with border folded in (replaces conv + fixup).
// Thread->pixel map reordered so border work fills dedicated waves:
//   tid 0..6003      : interior group (y=1+tid/38, x=4*(1+tid%38)) -- all 9
//                      taps of all 4 pixels are real pixels; fast path
//                      (identical inner loop to round-4 conv; float4 store).
//   tid 6016..6411   : one of the 396 border groups; per-pixel valid-masked
//                      taps (pad-cell VALUES never used -> no zeroing needed).
// ---------------------------------------------------------------------------
__global__ __launch_bounds__(256) void conv_kernel(const uint64_t* __restrict__ packed,
                                                   const uint64_t* __restrict__ wpack,
                                                   const float* __restrict__ alpha,
                                                   float* __restrict__ out) {
    const int t = blockIdx.x * 256 + threadIdx.x;
    const int b = blockIdx.y;
    const uint64_t* pimg = packed + (size_t)b * PPIX;
    float* oimg = out + (size_t)b * COUT_ * HWPIX;

    if (t < NINT) {
        // ---- fast interior path ----
        const int r = t / 38;              // 0..157
        const int c = t - r * 38;          // 0..37
        const int y = r + 1;               // 1..158
        const int x = (c + 1) * 4;         // 4..152 (pixels x..x+3 <= 155)
        // tap (ky,kx) of pixel (y,x) lives at padded(y+ky, x+kx) = pb[ky*PW+kx]
        const uint64_t* pb = pimg + (size_t)y * PW + x;

        uint64_t p[3][6];
#pragma unroll
        for (int ky = 0; ky < 3; ++ky)
#pragma unroll
            for (int kx = 0; kx < 6; ++kx)
                p[ky][kx] = pb[(size_t)ky * PW + kx];

        float* op = oimg + (size_t)y * WID + x;
#pragma unroll 4
        for (int co = 0; co < COUT_; ++co) {
            const uint64_t* wp = wpack + co * 9;
            int pc0 = 0, pc1 = 0, pc2 = 0, pc3 = 0;
#pragma unroll
            for (int ky = 0; ky < 3; ++ky)
#pragma unroll
                for (int kx = 0; kx < 3; ++kx) {
                    const uint64_t ww = wp[ky * 3 + kx];   // wave-uniform s_load
                    pc0 += __popcll(p[ky][kx + 0] ^ ww);
                    pc1 += __popcll(p[ky][kx + 1] ^ ww);
                    pc2 += __popcll(p[ky][kx + 2] ^ ww);
                    pc3 += __popcll(p[ky][kx + 3] ^ ww);
                }
            const float a = alpha[co];
            const float cc = 576.0f * a;
            const float m  = -2.0f * a;
            float4 rv;
            rv.x = fmaf((float)pc0, m, cc);
            rv.y = fmaf((float)pc1, m, cc);
            rv.z = fmaf((float)pc2, m, cc);
            rv.w = fmaf((float)pc3, m, cc);
            *(float4*)(op + (size_t)co * HWPIX) = rv;      // 16B-aligned
        }
    } else if (t >= BSTART && t < BSTART + NBORD) {
        // ---- border path: ~6.5 waves per image ----
        const int i = t - BSTART;
        int y, x4;
        if      (i < 40) { y = 0;   x4 = i * 4;        }
        else if (i < 80) { y = 159; x4 = (i - 40) * 4; }
        else {
            const int j = i - 80;           // 0..315
            y  = 1 + (j >> 1);              // 1..158
            x4 = (j & 1) * 156;             // 0 or 156
        }
#pragma unroll 1
        for (int px = 0; px < 4; ++px) {
            const int x = x4 + px;
            const uint64_t* pb = pimg + (size_t)y * PW + x;
            uint64_t p[9];
            int valid[9];
            int nv = 0;
#pragma unroll
            for (int ky = 0; ky < 3; ++ky)
#pragma unroll
                for (int kx = 0; kx < 3; ++kx) {
                    const int yy = y + ky - 1, xx = x + kx - 1;
                    const int v = (yy >= 0) && (yy < HEI) && (xx >= 0) && (xx < WID);
                    valid[ky * 3 + kx] = v;
                    nv += v;
                    p[ky * 3 + kx] = pb[(size_t)ky * PW + kx];  // in-bounds; value
                }                                               // used only if valid
            float* op = oimg + (size_t)y * WID + x;
            for (int co = 0; co < COUT_; ++co) {
                const uint64_t* wp = wpack + co * 9;
                int pc = 0;
#pragma unroll
                for (int tt = 0; tt < 9; ++tt)
                    pc += valid[tt] ? __popcll(p[tt] ^ wp[tt]) : 0;
                op[(size_t)co * HWPIX] = alpha[co] * (float)((nv << 6) - 2 * pc);
            }
        }
    }
}

// ---------------------------------------------------------------------------
extern "C" void kernel_launch(void* const* d_in, const int* in_sizes, int n_in,
                              void* d_out, int out_size, void* d_ws, size_t ws_size,
                              hipStream_t stream) {
    const float* x = (const float*)d_in[0];  // [32,64,160,160] f32
    const float* w = (const float*)d_in[1];  // [64,64,3,3] f32
    float* out = (float*)d_out;              // [32,64,160,160] f32

    uint64_t* wpack  = (uint64_t*)d_ws;                      // 4608 B
    float*    alpha  = (float*)((char*)d_ws + 4608);         // 256 B
    uint64_t* packed = (uint64_t*)((char*)d_ws + 8192);      // 32*26244*8 = 6.72 MB

    // 2 dispatches total. No memset anywhere: packed pad cells are never
    // value-read (interior path provably touches only real cells; border
    // path masks), so workspace poison in the pad ring is harmless.

    prep_kernel<<<dim3(26, BATCH), dim3(256), 0, stream>>>(x, w, packed, wpack, alpha);
    conv_kernel<<<dim3(26, BATCH), dim3(256), 0, stream>>>(packed, wpack, alpha, out);
}

// Round 7
// 438.368 us; speedup vs baseline: 1.1248x; 1.1248x over previous
//
#include <hip/hip_runtime.h>
#include <cstdint>

#define WID   160
#define HEI   160
#define HWPIX (WID * HEI)   // 25600
#define CIN_  64
#define COUT_ 64
#define BATCH 32
#define PW    162           // padded width/height (zero border)
#define PPIX  (PW * PW)     // 26244
#define NBORDER 636         // 2*160 + 2*158 border pixels per image

// ---------------------------------------------------------------------------
// Kernel 1: weight prep. One wave per output channel. lane = ci.
// ---------------------------------------------------------------------------
__global__ __launch_bounds__(64) void wprep_kernel(const float* __restrict__ w,
                                                   uint64_t* __restrict__ wpack,
                                                   float* __restrict__ alpha) {
    const int co = blockIdx.x;
    const int ci = threadIdx.x;
    const float* wp = w + ((size_t)co * CIN_ + ci) * 9;

    float vals[9];
    float s = 0.0f;
#pragma unroll
    for (int t = 0; t < 9; ++t) {
        float v = wp[t];
        vals[t] = v;
        s += fminf(fabsf(v), 1.0f);
    }
#pragma unroll
    for (int t = 0; t < 9; ++t) {
        unsigned long long m = __ballot(vals[t] > 0.0f);
        if (ci == 0) wpack[co * 9 + t] = m;
    }
#pragma unroll
    for (int off = 32; off > 0; off >>= 1) s += __shfl_down(s, off);
    if (ci == 0) alpha[co] = s * (1.0f / 576.0f);
}

// ---------------------------------------------------------------------------
// Kernel 2: binarize + channel-pack into zero-padded [b][162][162] u64 layout.
// Thread = 4 consecutive pixels. Block 0 of each image zeroes the border ring.
// ---------------------------------------------------------------------------
__global__ __launch_bounds__(256) void binpack_kernel(const float* __restrict__ x,
                                                      uint64_t* __restrict__ packed) {
    const int t  = blockIdx.x * 256 + threadIdx.x;   // 0..6399
    const int b  = blockIdx.y;
    uint64_t* pimg = packed + (size_t)b * PPIX;

    if (blockIdx.x == 0) {
        for (int j = threadIdx.x; j < PW; j += 256) {
            pimg[j] = 0;                              // top padded row
            pimg[(size_t)(PW - 1) * PW + j] = 0;      // bottom padded row
        }
        for (int r = threadIdx.x; r < HEI; r += 256) {
            pimg[(size_t)(r + 1) * PW] = 0;           // left padded col
            pimg[(size_t)(r + 1) * PW + (PW - 1)] = 0;// right padded col
        }
    }

    const int p4 = t * 4;
    const int y  = p4 / WID;
    const int x0 = p4 - y * WID;
    const float4* xp = (const float4*)(x + (size_t)b * CIN_ * HWPIX + p4);

    uint32_t lo[4] = {0, 0, 0, 0}, hi[4] = {0, 0, 0, 0};
#pragma unroll
    for (int ci = 0; ci < 32; ++ci) {
        float4 v = xp[(size_t)ci * (HWPIX / 4)];
        lo[0] |= (uint32_t)(v.x > 0.0f) << ci;
        lo[1] |= (uint32_t)(v.y > 0.0f) << ci;
        lo[2] |= (uint32_t)(v.z > 0.0f) << ci;
        lo[3] |= (uint32_t)(v.w > 0.0f) << ci;
    }
#pragma unroll
    for (int ci = 0; ci < 32; ++ci) {
        float4 v = xp[(size_t)(ci + 32) * (HWPIX / 4)];
        hi[0] |= (uint32_t)(v.x > 0.0f) << ci;
        hi[1] |= (uint32_t)(v.y > 0.0f) << ci;
        hi[2] |= (uint32_t)(v.z > 0.0f) << ci;
        hi[3] |= (uint32_t)(v.w > 0.0f) << ci;
    }
    uint64_t* dst = pimg + (size_t)(y + 1) * PW + (x0 + 1);
#pragma unroll
    for (int i = 0; i < 4; ++i)
        dst[i] = ((uint64_t)hi[i] << 32) | lo[i];
}

// ---------------------------------------------------------------------------
// Kernel 3: main conv. Thread = 4 consecutive pixels (p0 = 4t: contiguous
// full-image coverage -> full-cacheline coalesced float4 stores, no RMW).
// ROUND-7 CHANGE: __launch_bounds__(256, 2) (VGPR budget up to ~128) + taps
// in named const locals so all 18 stay register-resident across the co-loop.
// Round-6 evidence: this kernel compiled to VGPR_Count=32 -> tap reloads from
// L2 every co step -> 165 us at 34% VALUBusy. Registers fix the latency.
// Border ring wrong here (zero-pad formula); overwritten by fixup_kernel.
// ---------------------------------------------------------------------------
__global__ __launch_bounds__(256, 2) void conv_kernel(const uint64_t* __restrict__ packed,
                                                      const uint64_t* __restrict__ wpack,
                                                      const float* __restrict__ alpha,
                                                      float* __restrict__ out) {
    const int t4 = blockIdx.x * 256 + threadIdx.x;   // 0..6399 per image
    const int b  = blockIdx.y;
    const int p0 = t4 * 4;
    const int y  = p0 / WID;
    const int x  = p0 - y * WID;           // x in {0,4,...,156}
    const uint64_t* pb = packed + (size_t)b * PPIX + (size_t)y * PW + x;

    // 3 rows x 6 cols of taps, named locals -> register-resident
    const uint64_t p00 = pb[0],          p01 = pb[1],          p02 = pb[2];
    const uint64_t p03 = pb[3],          p04 = pb[4],          p05 = pb[5];
    const uint64_t p10 = pb[PW + 0],     p11 = pb[PW + 1],     p12 = pb[PW + 2];
    const uint64_t p13 = pb[PW + 3],     p14 = pb[PW + 4],     p15 = pb[PW + 5];
    const uint64_t p20 = pb[2 * PW + 0], p21 = pb[2 * PW + 1], p22 = pb[2 * PW + 2];
    const uint64_t p23 = pb[2 * PW + 3], p24 = pb[2 * PW + 4], p25 = pb[2 * PW + 5];

    float* op = out + (size_t)b * COUT_ * HWPIX + p0;
#pragma unroll 4
    for (int co = 0; co < COUT_; ++co) {
        const uint64_t* wp = wpack + co * 9;
        const uint64_t w0 = wp[0], w1 = wp[1], w2 = wp[2];
        const uint64_t w3 = wp[3], w4 = wp[4], w5 = wp[5];
        const uint64_t w6 = wp[6], w7 = wp[7], w8 = wp[8];

        int pc0 = __popcll(p00 ^ w0) + __popcll(p01 ^ w1) + __popcll(p02 ^ w2)
                + __popcll(p10 ^ w3) + __popcll(p11 ^ w4) + __popcll(p12 ^ w5)
                + __popcll(p20 ^ w6) + __popcll(p21 ^ w7) + __popcll(p22 ^ w8);
        int pc1 = __popcll(p01 ^ w0) + __popcll(p02 ^ w1) + __popcll(p03 ^ w2)
                + __popcll(p11 ^ w3) + __popcll(p12 ^ w4) + __popcll(p13 ^ w5)
                + __popcll(p21 ^ w6) + __popcll(p22 ^ w7) + __popcll(p23 ^ w8);
        int pc2 = __popcll(p02 ^ w0) + __popcll(p03 ^ w1) + __popcll(p04 ^ w2)
                + __popcll(p12 ^ w3) + __popcll(p13 ^ w4) + __popcll(p14 ^ w5)
                + __popcll(p22 ^ w6) + __popcll(p23 ^ w7) + __popcll(p24 ^ w8);
        int pc3 = __popcll(p03 ^ w0) + __popcll(p04 ^ w1) + __popcll(p05 ^ w2)
                + __popcll(p13 ^ w3) + __popcll(p14 ^ w4) + __popcll(p15 ^ w5)
                + __popcll(p23 ^ w6) + __popcll(p24 ^ w7) + __popcll(p25 ^ w8);

        const float a = alpha[co];
        const float c = 576.0f * a;
        const float m = -2.0f * a;
        float4 r;
        r.x = fmaf((float)pc0, m, c);
        r.y = fmaf((float)pc1, m, c);
        r.z = fmaf((float)pc2, m, c);
        r.w = fmaf((float)pc3, m, c);
        *(float4*)(op + (size_t)co * HWPIX) = r;       // 16B-aligned, coalesced
    }
}

// ---------------------------------------------------------------------------
// Kernel 4: exact recompute of the 636-pixel border ring, CO-PARALLEL:
// thread = one (border-pixel, co) pair; blockIdx.y = co.
// ---------------------------------------------------------------------------
__global__ __launch_bounds__(256) void fixup_kernel(const uint64_t* __restrict__ packed,
                                                    const uint64_t* __restrict__ wpack,
                                                    const float* __restrict__ alpha,
                                                    float* __restrict__ out) {
    const int t = blockIdx.x * 256 + threadIdx.x;
    if (t >= NBORDER * BATCH) return;
    const int co = blockIdx.y;
    const int b  = t / NBORDER;
    const int i  = t - b * NBORDER;
    int x, y;
    if      (i < 160) { y = 0;       x = i;       }
    else if (i < 320) { y = 159;     x = i - 160; }
    else if (i < 478) { x = 0;       y = i - 319; }  // y = 1..158
    else              { x = 159;     y = i - 477; }  // y = 1..158

    const uint64_t* pb = packed + (size_t)b * PPIX + (size_t)y * PW + x;
    const uint64_t* wp = wpack + co * 9;
    int pc = 0, nv = 0;
#pragma unroll
    for (int ky = 0; ky < 3; ++ky)
#pragma unroll
        for (int kx = 0; kx < 3; ++kx) {
            const int yy = y + ky - 1, xx = x + kx - 1;
            const int v = (yy >= 0) && (yy < HEI) && (xx >= 0) && (xx < WID);
            const uint64_t pt = pb[(size_t)ky * PW + kx];  // in-bounds (pad ring)
            nv += v;
            pc += v ? __popcll(pt ^ wp[ky * 3 + kx]) : 0;
        }
    out[(size_t)b * COUT_ * HWPIX + (size_t)co * HWPIX + (size_t)y * WID + x] =
        alpha[co] * (float)((nv << 6) - 2 * pc);
}

// ---------------------------------------------------------------------------
extern "C" void kernel_launch(void* const* d_in, const int* in_sizes, int n_in,
                              void* d_out, int out_size, void* d_ws, size_t ws_size,
                              hipStream_t stream) {
    const float* x = (const float*)d_in[0];  // [32,64,160,160] f32
    const float* w = (const float*)d_in[1];  // [64,64,3,3] f32
    float* out = (float*)d_out;              // [32,64,160,160] f32

    uint64_t* wpack  = (uint64_t*)d_ws;                      // 4608 B
    float*    alpha  = (float*)((char*)d_ws + 4608);         // 256 B
    uint64_t* packed = (uint64_t*)((char*)d_ws + 8192);      // 32*26244*8 = 6.72 MB

    // no memset: binpack block 0 zeroes the padded border ring per image.

    wprep_kernel<<<dim3(COUT_), dim3(64), 0, stream>>>(w, wpack, alpha);
    binpack_kernel<<<dim3(HWPIX / 4 / 256, BATCH), dim3(256), 0, stream>>>(x, packed);
    conv_kernel<<<dim3(HWPIX / 4 / 256, BATCH), dim3(256), 0, stream>>>(packed, wpack, alpha, out);
    fixup_kernel<<<dim3((NBORDER * BATCH + 255) / 256, COUT_), dim3(256), 0, stream>>>(packed, wpack, alpha, out);
}